// Round 1
// baseline (55.316 us; speedup 1.0000x reference)
//
#include <hip/hip_runtime.h>

// Problem constants (from reference): B=32, R=3136 (=56*56), O=20, D=32.
#define NB 32
#define NR 3136
#define NO 20
#define ND 32
#define RAYS_PER_BLOCK 8   // 256 threads / 32 lanes-per-ray

// One ray per 32-lane half-wave. Lane o (<20) owns depth/trans of object o;
// lane d (<32) owns output channel d. Cross-lane data via width-32 shuffles.
__global__ __launch_bounds__(256) void ray_composite(
    const float* __restrict__ form,    // [B,R,O,D]
    const float* __restrict__ depth,   // [B,R,O]
    const float* __restrict__ trans,   // [B,R,O]
    float* __restrict__ out_res,       // [B,D,H,W]  (R == H*W)
    float* __restrict__ out_pond)      // [B,R,O]
{
  const int ray  = blockIdx.x * RAYS_PER_BLOCK + (threadIdx.x >> 5);
  const int lane = threadIdx.x & 31;
  const int b = ray / NR;
  const int r = ray - b * NR;

  const float* dep = depth + (size_t)ray * NO;
  const float* trs = trans + (size_t)ray * NO;

  float d_o = 0.0f, t_o = 0.0f;
  if (lane < NO) { d_o = dep[lane]; t_o = trs[lane]; }

  // acc[o] = sum_j trans[j] * sigmoid(1000*(depth[o]-depth[j])), j != o
  float acc = 0.0f;
#pragma unroll
  for (int j = 0; j < NO; ++j) {
    const float dj = __shfl(d_o, j, 32);
    const float tj = __shfl(t_o, j, 32);
    const float s  = 1.0f / (1.0f + __expf(-1000.0f * (d_o - dj)));
    if (j != lane) acc += tj * s;
  }

  float pond = __expf(acc) * (1.0f - __expf(t_o));
  if (lane >= NO) pond = 0.0f;
  if (lane < NO) out_pond[(size_t)ray * NO + lane] = pond;

  // result[d] = sum_o pond[o] * form[o][d]; lane d reads coalesced 128B rows.
  const float* f = form + (size_t)ray * (NO * ND);
  float res = 0.0f;
#pragma unroll
  for (int o = 0; o < NO; ++o) {
    const float p = __shfl(pond, o, 32);
    res += p * f[o * ND + lane];
  }

  // [b,r,d] -> [b,d,h,w]: out index = b*D*R + d*R + r  (stride-R scatter)
  out_res[(size_t)b * (ND * NR) + (size_t)lane * NR + r] = res;
}

extern "C" void kernel_launch(void* const* d_in, const int* in_sizes, int n_in,
                              void* d_out, int out_size, void* d_ws, size_t ws_size,
                              hipStream_t stream) {
  const float* form  = (const float*)d_in[0];  // [B,R,O,D] fp32
  const float* depth = (const float*)d_in[1];  // [B,R,O]   fp32
  const float* trans = (const float*)d_in[2];  // [B,R,O]   fp32

  float* out_res  = (float*)d_out;                       // [B,D,H,W]
  float* out_pond = out_res + (size_t)NB * ND * NR;      // [B,R,O]

  const int nrays = NB * NR;                 // 100352
  dim3 grid(nrays / RAYS_PER_BLOCK);         // 12544
  dim3 block(256);
  ray_composite<<<grid, block, 0, stream>>>(form, depth, trans, out_res, out_pond);
}

// Round 2
// 50.084 us; speedup vs baseline: 1.1045x; 1.1045x over previous
//
#include <hip/hip_runtime.h>

// B=32, R=3136 (=56*56), O=20, D=32. Memory-bound: ~294 MB traffic.
#define NB 32
#define NR 3136
#define NO 20
#define ND 32
#define RPB 16            // rays per block (NR % RPB == 0 -> no batch straddle)
#define BLOCK (RPB * 32)  // 512

__global__ __launch_bounds__(BLOCK) void ray_composite(
    const float* __restrict__ form,    // [B,R,O,D]
    const float* __restrict__ depth,   // [B,R,O]
    const float* __restrict__ trans,   // [B,R,O]
    float* __restrict__ out_res,       // [B,D,H,W]
    float* __restrict__ out_pond)      // [B,R,O]
{
  __shared__ float res_lds[RPB][36];     // pad 32->36: float4-aligned, 2-way max
  __shared__ float pond_lds[RPB * NO];

  const int t    = threadIdx.x;
  const int rib  = t >> 5;               // ray index within block
  const int lane = t & 31;
  const int ray0 = blockIdx.x * RPB;
  const int ray  = ray0 + rib;
  const int b    = ray0 / NR;
  const int r0   = ray0 - b * NR;

  // ---- phase 1: ponderation (lane o<20 owns object o of its ray) ----
  float d_o = 0.f, t_o = 0.f;
  if (lane < NO) {
    d_o = depth[(size_t)ray * NO + lane];
    t_o = trans[(size_t)ray * NO + lane];
  }
  float acc = 0.f;
#pragma unroll
  for (int j = 0; j < NO; ++j) {
    const float dj = __shfl(d_o, j, 32);
    const float tj = __shfl(t_o, j, 32);
    const float s  = 1.f / (1.f + __expf(-1000.f * (d_o - dj)));
    if (j != lane) acc += tj * s;
  }
  float pond = __expf(acc) * (1.f - __expf(t_o));
  if (lane >= NO) pond = 0.f;
  if (lane < NO) pond_lds[rib * NO + lane] = pond;

  // ---- phase 2: res[d] = sum_o pond[o]*form[o][d], float4 loads ----
  // lane = og*8 + c: chunk c holds channels 4c..4c+3; row-group og covers
  // objects {og, og+4, og+8, og+12, og+16}. Half-wave reads contiguous 512B.
  const int c  = lane & 7;
  const int og = lane >> 3;
  const float* fbase = form + (size_t)ray * (NO * ND);
  float4 accv = make_float4(0.f, 0.f, 0.f, 0.f);
#pragma unroll
  for (int k = 0; k < 5; ++k) {
    const int o = og + 4 * k;
    const float p = __shfl(pond, o, 32);
    const float4 v = *reinterpret_cast<const float4*>(fbase + o * ND + c * 4);
    accv.x += p * v.x; accv.y += p * v.y; accv.z += p * v.z; accv.w += p * v.w;
  }
#pragma unroll
  for (int m = 8; m <= 16; m <<= 1) {   // reduce across the 4 row-groups
    accv.x += __shfl_xor(accv.x, m, 32);
    accv.y += __shfl_xor(accv.y, m, 32);
    accv.z += __shfl_xor(accv.z, m, 32);
    accv.w += __shfl_xor(accv.w, m, 32);
  }
  if (lane < 8)
    *reinterpret_cast<float4*>(&res_lds[rib][lane * 4]) = accv;

  __syncthreads();

  // ---- phase 3: coalesced stores ----
  // result: per d, 16 consecutive floats (full 64B line per block)
  {
    const int d  = t >> 4;
    const int rr = t & 15;
    out_res[(size_t)b * (ND * NR) + (size_t)d * NR + r0 + rr] = res_lds[rr][d];
  }
  // ponderation: one contiguous 1280B run per block
  if (t < RPB * NO)
    out_pond[(size_t)ray0 * NO + t] = pond_lds[t];
}

extern "C" void kernel_launch(void* const* d_in, const int* in_sizes, int n_in,
                              void* d_out, int out_size, void* d_ws, size_t ws_size,
                              hipStream_t stream) {
  const float* form  = (const float*)d_in[0];
  const float* depth = (const float*)d_in[1];
  const float* trans = (const float*)d_in[2];

  float* out_res  = (float*)d_out;
  float* out_pond = out_res + (size_t)NB * ND * NR;

  dim3 grid((NB * NR) / RPB);   // 6272
  dim3 block(BLOCK);            // 512
  ray_composite<<<grid, block, 0, stream>>>(form, depth, trans, out_res, out_pond);
}